// Round 1
// baseline (211.009 us; speedup 1.0000x reference)
//
#include <hip/hip_runtime.h>
#include <hip/hip_bf16.h>
#include <stdint.h>

// CapsuleLayer dynamic routing, MI355X.
// Shapes: B=64, I=2048, P=16, J=32, D=16. ROUTINGS=3.
// Plan: materialize u_hat in bf16 (128MB ws), then 3x identical routing passes
// (logits = dot(u_hat, vsum) since b-logits start at 0 => b_r = dot(u, v0+..+v_{r-1})).

namespace {
constexpr int B_ = 64;
constexpr int I_ = 2048;
constexpr int P_ = 16;
constexpr int J_ = 32;
constexpr int D_ = 16;
constexpr int CI_ = 128;   // i-range per routing block

__device__ __forceinline__ float bflo(uint32_t v) {
  union { uint32_t u; float f; } z; z.u = v << 16; return z.f;
}
__device__ __forceinline__ float bfhi(uint32_t v) {
  union { uint32_t u; float f; } z; z.u = v & 0xffff0000u; return z.f;
}

// ---------------------------------------------------------------------------
// K0: u_hat[b,i,j,d] = sum_p x[b,i,p] * W[i,j,d,p], stored bf16.
// grid = I blocks x 256 threads. Thread t owns output rows {2t, 2t+1} of the
// 512 (j*16+d) rows for this i: W rows live in 32 VGPRs, x broadcast from LDS.
// ---------------------------------------------------------------------------
__global__ __launch_bounds__(256) void k_uhat(const float* __restrict__ x,
                                              const float* __restrict__ W,
                                              __hip_bfloat162* __restrict__ uhat) {
  const int i = blockIdx.x;
  const int t = threadIdx.x;
  __shared__ float xs[B_][P_];  // 4KB; reads are wave-uniform (broadcast, no conflicts)
  {
    const int b = t >> 2, c = t & 3;
    const float4 v = *reinterpret_cast<const float4*>(
        x + (size_t)b * (I_ * P_) + (size_t)i * P_ + c * 4);
    *reinterpret_cast<float4*>(&xs[b][c * 4]) = v;
  }
  // W rows 2t, 2t+1: 128B contiguous per thread, coalesced across the wave.
  float w0[P_], w1[P_];
  const float* Wi = W + (size_t)i * (J_ * D_ * P_);
#pragma unroll
  for (int c = 0; c < 4; ++c) {
    *reinterpret_cast<float4*>(&w0[c * 4]) =
        *reinterpret_cast<const float4*>(Wi + (2 * t + 0) * P_ + c * 4);
    *reinterpret_cast<float4*>(&w1[c * 4]) =
        *reinterpret_cast<const float4*>(Wi + (2 * t + 1) * P_ + c * 4);
  }
  __syncthreads();
  __hip_bfloat162* dst = uhat + (size_t)i * (J_ * D_ / 2) + t;  // + b*I*256 later
#pragma unroll 4
  for (int b = 0; b < B_; ++b) {
    const float4* xb = reinterpret_cast<const float4*>(&xs[b][0]);
    const float4 x0 = xb[0], x1 = xb[1], x2 = xb[2], x3 = xb[3];
    const float xr[P_] = {x0.x, x0.y, x0.z, x0.w, x1.x, x1.y, x1.z, x1.w,
                          x2.x, x2.y, x2.z, x2.w, x3.x, x3.y, x3.z, x3.w};
    float a0 = 0.f, a1 = 0.f;
#pragma unroll
    for (int p = 0; p < P_; ++p) {
      a0 = fmaf(xr[p], w0[p], a0);
      a1 = fmaf(xr[p], w1[p], a1);
    }
    __hip_bfloat162 pk;
    pk.x = __float2bfloat16(a0);
    pk.y = __float2bfloat16(a1);
    dst[(size_t)b * (I_ * J_ * D_ / 2)] = pk;  // 4B coalesced store across t
  }
}

// ---------------------------------------------------------------------------
// K_route: one routing pass.
//   logit[b,i,j] = sum_d u_hat[b,i,j,d] * vsum[b,j,d]
//   c = softmax_j(logit);  s[b,j,d] += sum_i c * u_hat[b,i,j,d]
// grid = (I/CI, B) x 256 threads. lane&31 = j; 32-lane shfl softmax groups.
// Per-lane register accumulator over the block's i-range, then LDS reduce +
// 512 atomicAdds per block.
// ---------------------------------------------------------------------------
__global__ __launch_bounds__(256) void k_route(const uint4* __restrict__ uhat,
                                               const float* __restrict__ vsum,
                                               float* __restrict__ s) {
  const int b = blockIdx.y;
  const int i0 = blockIdx.x * CI_;
  const int t = threadIdx.x;
  const int lane = t & 63;
  const int wave = t >> 6;   // 0..3
  const int sub = lane >> 5; // which i of the wave's pair
  const int j = lane & 31;

  float vr[D_];
  {
    const float4* vp = reinterpret_cast<const float4*>(vsum + ((size_t)b * J_ + j) * D_);
#pragma unroll
    for (int c = 0; c < 4; ++c) {
      const float4 v = vp[c];
      vr[c * 4 + 0] = v.x; vr[c * 4 + 1] = v.y;
      vr[c * 4 + 2] = v.z; vr[c * 4 + 3] = v.w;
    }
  }
  float acc[D_];
#pragma unroll
  for (int d = 0; d < D_; ++d) acc[d] = 0.f;

  for (int it = 0; it < CI_ / 8; ++it) {
    const int i = i0 + it * 8 + wave * 2 + sub;
    const uint4* up = uhat + (((size_t)b * I_ + i) * J_ + j) * 2;  // 32B row, contiguous per wave
    const uint4 q0 = up[0], q1 = up[1];
    float u[D_];
    u[0] = bflo(q0.x);  u[1] = bfhi(q0.x);  u[2] = bflo(q0.y);  u[3] = bfhi(q0.y);
    u[4] = bflo(q0.z);  u[5] = bfhi(q0.z);  u[6] = bflo(q0.w);  u[7] = bfhi(q0.w);
    u[8] = bflo(q1.x);  u[9] = bfhi(q1.x);  u[10] = bflo(q1.y); u[11] = bfhi(q1.y);
    u[12] = bflo(q1.z); u[13] = bfhi(q1.z); u[14] = bflo(q1.w); u[15] = bfhi(q1.w);

    float lg = 0.f;
#pragma unroll
    for (int d = 0; d < D_; ++d) lg = fmaf(u[d], vr[d], lg);
    // softmax over the 32 j-lanes
    float m = lg;
#pragma unroll
    for (int off = 16; off > 0; off >>= 1) m = fmaxf(m, __shfl_xor(m, off, 32));
    const float e = __expf(lg - m);
    float sm = e;
#pragma unroll
    for (int off = 16; off > 0; off >>= 1) sm += __shfl_xor(sm, off, 32);
    const float c = e / sm;
#pragma unroll
    for (int d = 0; d < D_; ++d) acc[d] = fmaf(c, u[d], acc[d]);
  }
  // combine the wave's two i-substreams (lane l <-> l^32, same j)
#pragma unroll
  for (int d = 0; d < D_; ++d) acc[d] += __shfl_xor(acc[d], 32, 64);

  __shared__ float sp[4][J_][D_ + 1];  // +1 pad: conflict-free column writes
  if (sub == 0) {
#pragma unroll
    for (int d = 0; d < D_; ++d) sp[wave][j][d] = acc[d];
  }
  __syncthreads();
  for (int k = t; k < J_ * D_; k += 256) {
    const int jj = k >> 4, dd = k & 15;
    atomicAdd(s + (size_t)b * (J_ * D_) + k,
              sp[0][jj][dd] + sp[1][jj][dd] + sp[2][jj][dd] + sp[3][jj][dd]);
  }
}

// ---------------------------------------------------------------------------
// K_squash: v = squash(s); optionally vsum += v; optionally write out.
// ---------------------------------------------------------------------------
__global__ __launch_bounds__(256) void k_squash(const float* __restrict__ s,
                                                float* __restrict__ vsum,
                                                float* __restrict__ out) {
  const int r = blockIdx.x * 256 + threadIdx.x;  // row over B*J
  if (r >= B_ * J_) return;
  const float4* sp = reinterpret_cast<const float4*>(s + (size_t)r * D_);
  float4 a[4] = {sp[0], sp[1], sp[2], sp[3]};
  float n2 = 1e-7f;  // EPS
#pragma unroll
  for (int c = 0; c < 4; ++c)
    n2 += a[c].x * a[c].x + a[c].y * a[c].y + a[c].z * a[c].z + a[c].w * a[c].w;
  const float sc = n2 / ((1.f + n2) * sqrtf(n2));
#pragma unroll
  for (int c = 0; c < 4; ++c) {
    a[c].x *= sc; a[c].y *= sc; a[c].z *= sc; a[c].w *= sc;
  }
  if (vsum) {
    float4* vp = reinterpret_cast<float4*>(vsum + (size_t)r * D_);
#pragma unroll
    for (int c = 0; c < 4; ++c) {
      float4 v = vp[c];
      v.x += a[c].x; v.y += a[c].y; v.z += a[c].z; v.w += a[c].w;
      vp[c] = v;
    }
  }
  if (out) {
    float4* op = reinterpret_cast<float4*>(out + (size_t)r * D_);
#pragma unroll
    for (int c = 0; c < 4; ++c) op[c] = a[c];
  }
}

}  // namespace

extern "C" void kernel_launch(void* const* d_in, const int* in_sizes, int n_in,
                              void* d_out, int out_size, void* d_ws, size_t ws_size,
                              hipStream_t stream) {
  const float* x = (const float*)d_in[0];   // [B, I, P] fp32
  const float* W = (const float*)d_in[1];   // [I, J, D, P] fp32 (einsum 'ijdp')
  float* out = (float*)d_out;               // [B, J, D] fp32

  char* ws = (char*)d_ws;
  __hip_bfloat162* uhat = (__hip_bfloat162*)ws;                 // 128 MB
  const size_t UHAT_BYTES = (size_t)B_ * I_ * J_ * D_ * 2;
  float* s0 = (float*)(ws + UHAT_BYTES);                        // [B,J,D]
  float* s1 = s0 + B_ * J_ * D_;
  float* s2 = s1 + B_ * J_ * D_;
  float* vsum = s2 + B_ * J_ * D_;                              // running v0+v1

  // zero s0,s1,s2,vsum (ws is poisoned 0xAA before every timed launch)
  hipMemsetAsync(s0, 0, (size_t)4 * B_ * J_ * D_ * sizeof(float), stream);

  k_uhat<<<I_, 256, 0, stream>>>(x, W, uhat);

  const dim3 rg(I_ / CI_, B_);
  // pass 0: vsum = 0 -> logits 0 -> uniform softmax (matches c = softmax(b=0))
  k_route<<<rg, 256, 0, stream>>>((const uint4*)uhat, vsum, s0);
  k_squash<<<(B_ * J_ + 255) / 256, 256, 0, stream>>>(s0, vsum, nullptr);
  // pass 1: logits vs v0
  k_route<<<rg, 256, 0, stream>>>((const uint4*)uhat, vsum, s1);
  k_squash<<<(B_ * J_ + 255) / 256, 256, 0, stream>>>(s1, vsum, nullptr);
  // pass 2: logits vs v0+v1 (b2 = dot(u,v0)+dot(u,v1))
  k_route<<<rg, 256, 0, stream>>>((const uint4*)uhat, vsum, s2);
  k_squash<<<(B_ * J_ + 255) / 256, 256, 0, stream>>>(s2, nullptr, out);
}